// Round 4
// baseline (223.894 us; speedup 1.0000x reference)
//
#include <hip/hip_runtime.h>
#include <hip/hip_bf16.h>
#include <stdint.h>

#define NUM_TOKENS 8192
#define HIDDEN 1024
#define NEXP 8
#define TOPK 2

typedef __bf16 bf16;
typedef __bf16 bf16x4 __attribute__((ext_vector_type(4)));
typedef __bf16 bf16x8 __attribute__((ext_vector_type(8)));
typedef float f32x4 __attribute__((ext_vector_type(4)));

// global -> LDS direct copy, 16B per lane. LDS dest must be lane-contiguous.
__device__ __forceinline__ void gld_lds16(const void* g, void* l) {
  __builtin_amdgcn_global_load_lds(
      (const __attribute__((address_space(1))) void*)(uintptr_t)g,
      (__attribute__((address_space(3))) void*)(uint32_t)(uintptr_t)l,
      16, 0, 0);
}

// ---------------------------------------------------------------------------
// Kernel 1 "prep": three independent jobs fused into one launch.
//   blocks [0,2048):    gating (fp32 exact) + x fp32->bf16     (one wave/token)
//   blocks [2048,4096): expert weights fp32->bf16              (16 elem/thread)
//   blocks [4096,6144): zero out                                (16 f32/thread)
// ---------------------------------------------------------------------------
__global__ __launch_bounds__(256) void prep_kernel(
    const float* __restrict__ x, const float* __restrict__ gw,
    const float* __restrict__ ew,
    bf16* __restrict__ xbf, bf16* __restrict__ wbf,
    int* __restrict__ echoice, float* __restrict__ pchoice,
    float* __restrict__ out)
{
  const int b   = blockIdx.x;
  const int tid = threadIdx.x;

  if (b < 2048) {
    // ---- gating + xbf ----
    const int wid  = tid >> 6;
    const int lane = tid & 63;
    const int t = b * 4 + wid;   // t in [0, 8192)

    const float* xrow = x + (size_t)t * HIDDEN;
    bf16* xbrow = xbf + (size_t)t * HIDDEN;

    float acc[NEXP];
#pragma unroll
    for (int e = 0; e < NEXP; ++e) acc[e] = 0.f;

#pragma unroll
    for (int it = 0; it < 4; ++it) {
      const int idx = it * 256 + lane * 4;
      float4 xv = *(const float4*)(xrow + idx);
      bf16x4 xb;
      xb[0] = (bf16)xv.x; xb[1] = (bf16)xv.y; xb[2] = (bf16)xv.z; xb[3] = (bf16)xv.w;
      *(bf16x4*)(xbrow + idx) = xb;
#pragma unroll
      for (int e = 0; e < NEXP; ++e) {
        float4 gv = *(const float4*)(gw + e * HIDDEN + idx);
        acc[e] += xv.x * gv.x + xv.y * gv.y + xv.z * gv.z + xv.w * gv.w;
      }
    }
#pragma unroll
    for (int e = 0; e < NEXP; ++e) {
#pragma unroll
      for (int off = 32; off > 0; off >>= 1)
        acc[e] += __shfl_xor(acc[e], off, 64);
    }

    if (lane == 0) {
      float m = acc[0];
#pragma unroll
      for (int e = 1; e < NEXP; ++e) m = fmaxf(m, acc[e]);
      float p[NEXP]; float s = 0.f;
#pragma unroll
      for (int e = 0; e < NEXP; ++e) { p[e] = expf(acc[e] - m); s += p[e]; }
      const float inv = 1.f / s;
#pragma unroll
      for (int e = 0; e < NEXP; ++e) p[e] *= inv;
      // top-2, ties -> lower index (jax.lax.top_k semantics)
      int i0 = 0; float p0 = p[0];
#pragma unroll
      for (int e = 1; e < NEXP; ++e) if (p[e] > p0) { p0 = p[e]; i0 = e; }
      int i1 = -1; float p1 = -1.f;
#pragma unroll
      for (int e = 0; e < NEXP; ++e) if (e != i0 && p[e] > p1) { p1 = p[e]; i1 = e; }

      echoice[t]              = i0;
      echoice[NUM_TOKENS + t] = i1;
      pchoice[t]              = p0;
      pchoice[NUM_TOKENS + t] = p1;
    }
  } else if (b < 4096) {
    // ---- expert weights fp32 -> bf16, 16 elems/thread ----
    const size_t i = ((size_t)(b - 2048) * 256 + tid) * 16;
    float4 v0 = *(const float4*)(ew + i);
    float4 v1 = *(const float4*)(ew + i + 4);
    float4 v2 = *(const float4*)(ew + i + 8);
    float4 v3 = *(const float4*)(ew + i + 12);
    bf16x8 o0, o1;
    o0[0] = (bf16)v0.x; o0[1] = (bf16)v0.y; o0[2] = (bf16)v0.z; o0[3] = (bf16)v0.w;
    o0[4] = (bf16)v1.x; o0[5] = (bf16)v1.y; o0[6] = (bf16)v1.z; o0[7] = (bf16)v1.w;
    o1[0] = (bf16)v2.x; o1[1] = (bf16)v2.y; o1[2] = (bf16)v2.z; o1[3] = (bf16)v2.w;
    o1[4] = (bf16)v3.x; o1[5] = (bf16)v3.y; o1[6] = (bf16)v3.z; o1[7] = (bf16)v3.w;
    *(bf16x8*)(wbf + i)     = o0;
    *(bf16x8*)(wbf + i + 8) = o1;
  } else {
    // ---- zero out (for the atomic GEMM epilogue), 16 f32/thread ----
    const size_t i = ((size_t)(b - 4096) * 256 + tid) * 16;
    const float4 z = {0.f, 0.f, 0.f, 0.f};
    *(float4*)(out + i)      = z;
    *(float4*)(out + i + 4)  = z;
    *(float4*)(out + i + 8)  = z;
    *(float4*)(out + i + 12) = z;
  }
}

// ---------------------------------------------------------------------------
// Kernel 1b: DETERMINISTIC compaction, 16 blocks (one per (k,expert) list).
// ---------------------------------------------------------------------------
__global__ __launch_bounds__(1024) void build_lists_kernel(
    const int* __restrict__ echoice, const float* __restrict__ pchoice,
    int* __restrict__ cnt, int* __restrict__ tok, float* __restrict__ wt)
{
  const int list = blockIdx.x;         // 0..15
  const int k = list >> 3;
  const int e = list & 7;
  const int tid  = threadIdx.x;
  const int wave = tid >> 6;           // 0..15
  const int lane = tid & 63;
  const int tbase = wave * 512;

  const int*   ec = echoice + k * NUM_TOKENS;
  const float* pc = pchoice + k * NUM_TOKENS;

  __shared__ int wcnt[16];
  __shared__ int woff[16];

  const unsigned long long lower = ((unsigned long long)1 << lane) - 1;

  int   ev[8];
  float pv[8];
#pragma unroll
  for (int c = 0; c < 8; ++c) {
    ev[c] = ec[tbase + c * 64 + lane];
    pv[c] = pc[tbase + c * 64 + lane];
  }
  unsigned long long m[8];
  int cl = 0;
#pragma unroll
  for (int c = 0; c < 8; ++c) { m[c] = __ballot(ev[c] == e); cl += __popcll(m[c]); }
  if (lane == 0) wcnt[wave] = cl;
  __syncthreads();
  if (tid == 0) {
    int off = 0;
#pragma unroll
    for (int w = 0; w < 16; ++w) { woff[w] = off; off += wcnt[w]; }
    cnt[list] = off;
  }
  __syncthreads();
  int run = woff[wave];
#pragma unroll
  for (int c = 0; c < 8; ++c) {
    if (ev[c] == e) {
      const int pos = run + __popcll(m[c] & lower);
      tok[(size_t)list * NUM_TOKENS + pos] = tbase + c * 64 + lane;
      wt [(size_t)list * NUM_TOKENS + pos] = pv[c];
    }
    run += __popcll(m[c]);
  }
}

// ---------------------------------------------------------------------------
// Kernel 2: grouped GEMM, 256x256 tile (round-4 lesson: the 128x128 tile was
// bounded by per-CU L2 delivery share -- 16KB staged per K-step vs 80cyc of
// MFMA caps MfmaUtil at ~27%; counted-vmcnt depth was null because bandwidth,
// not latency, was binding. 256^2 doubles FLOP per staged byte: total L2
// staging traffic 1GB -> 512MB, floor ~15us ~ MFMA floor ~14us).
//   - 512 threads = 8 waves (2M x 4N); per-wave output 128x64 (HK geometry)
//   - BK=32, QUAD-buffered (4 x 32KB = 128KB LDS, 1 block/CU), depth-3
//     prefetch, counted vmcnt(8) at the per-tile barrier (round-3-verified
//     loop, geometry scaled)
//   - XOR swizzle chunk ^= (row>>1)&3 on 64B rows -> 2-way residual (free);
//     source pre-swizzled, LDS linear (rule #21)
//   - T5 setprio around the 32-MFMA cluster
// Epilogue: native fp32 atomicAdd into zeroed out; exactly 2 contributions
// per element (one per top-k slot); fp32 add commutative -> deterministic.
// ---------------------------------------------------------------------------
__global__ __launch_bounds__(512, 2) void moe_gemm_kernel(
    const bf16* __restrict__ xbf, const bf16* __restrict__ wbf,
    const int* __restrict__ cnt, const int* __restrict__ tok,
    const float* __restrict__ wt, float* __restrict__ out)
{
  const int e  = blockIdx.z >> 1;
  const int k  = blockIdx.z & 1;
  const int list = k * NEXP + e;
  const int mt = blockIdx.y;
  const int nt = blockIdx.x;
  const int count = cnt[list];
  const int m0 = mt * 256;
  if (m0 >= count) return;
  const int rows = min(256, count - m0);

  __shared__ __align__(16) bf16 As[4 * 256 * 32];   // 4 x 16KB
  __shared__ __align__(16) bf16 Bs[4 * 256 * 32];   // 4 x 16KB
  __shared__ int   tok_s[256];
  __shared__ float wt_s[256];

  const int tid = threadIdx.x;
  if (tid < 256) {
    if (tid < rows) {
      tok_s[tid] = tok[(size_t)list * NUM_TOKENS + m0 + tid];
      wt_s[tid]  = wt [(size_t)list * NUM_TOKENS + m0 + tid];
    } else { tok_s[tid] = 0; wt_s[tid] = 0.f; }
  }
  __syncthreads();

  // staging: thread -> rows (tid>>2) and (tid>>2)+128, phys chunk tid&3.
  // LDS dest LINEAR (tid*16B; pass 1 at +4096 elems = rows [128,256)).
  // Source carries the inverse swizzle: srcChunk = (tid&3) ^ ((row>>1)&3);
  // (row>>1)&3 == (tid>>3)&3 for both passes (128 ≡ 0 mod 8).
  const int csrc = (((tid & 3) ^ ((tid >> 3) & 3)) << 3);  // elems
  const int r0 = tid >> 2;                                 // [0,128)
  const bf16* gA0 = xbf + (size_t)tok_s[r0] * HIDDEN + csrc;
  const bf16* gA1 = xbf + (size_t)tok_s[r0 + 128] * HIDDEN + csrc;
  const bf16* gB0 = wbf + (size_t)e * HIDDEN * HIDDEN
                  + (size_t)(nt * 256 + r0) * HIDDEN + csrc;
  const bf16* gB1 = gB0 + (size_t)128 * HIDDEN;

  auto STAGE = [&](int t, int buf) {
    const int kc = t << 5;
    bf16* la = As + buf * 8192 + tid * 8;
    bf16* lb = Bs + buf * 8192 + tid * 8;
    gld_lds16(gA0 + kc, la);
    gld_lds16(gA1 + kc, la + 4096);
    gld_lds16(gB0 + kc, lb);
    gld_lds16(gB1 + kc, lb + 4096);
  };

  const int wid  = tid >> 6;           // 0..7
  const int lane = tid & 63;
  const int wm = (wid >> 2) * 128;     // wave M-origin: 0 / 128
  const int wn = (wid & 3) * 64;       // wave N-origin: 0/64/128/192
  const int qm = lane & 15;            // m (or n) within 16
  const int l4 = lane >> 4;            // 8-elem k-chunk within 32

  f32x4 acc[8][4];
#pragma unroll
  for (int i = 0; i < 8; ++i)
#pragma unroll
    for (int j = 0; j < 4; ++j) acc[i][j] = (f32x4){0.f, 0.f, 0.f, 0.f};

  auto COMPUTE = [&](int buf) {
    const bf16* Ab = As + buf * 8192;
    const bf16* Bb = Bs + buf * 8192;
    bf16x8 a[8], b[4];
#pragma unroll
    for (int i = 0; i < 8; ++i) {
      const int r = wm + i * 16 + qm;
      a[i] = *(const bf16x8*)(Ab + r * 32 + ((l4 ^ ((r >> 1) & 3)) << 3));
    }
#pragma unroll
    for (int j = 0; j < 4; ++j) {
      const int r = wn + j * 16 + qm;
      b[j] = *(const bf16x8*)(Bb + r * 32 + ((l4 ^ ((r >> 1) & 3)) << 3));
    }
    __builtin_amdgcn_s_setprio(1);
#pragma unroll
    for (int i = 0; i < 8; ++i)
#pragma unroll
      for (int j = 0; j < 4; ++j)
        acc[i][j] = __builtin_amdgcn_mfma_f32_16x16x32_bf16(a[i], b[j], acc[i][j], 0, 0, 0);
    __builtin_amdgcn_s_setprio(0);
  };

  // prologue: 3 stages (12 loads/thread) in flight
  STAGE(0, 0); STAGE(1, 1); STAGE(2, 2);

  // main loop: K=1024 -> 32 tiles of BK=32; steady state keeps 2 stages
  // (8 loads/thread) in flight across every barrier.
#pragma unroll 1
  for (int t = 0; t < 29; ++t) {
    asm volatile("s_waitcnt vmcnt(8)" ::: "memory");  // my stage-t loads done
    __builtin_amdgcn_s_barrier();                     // everyone's stage-t done
    STAGE(t + 3, (t + 3) & 3);                        // overwrite buf[t-1]
    COMPUTE(t & 3);
  }
  // tail: drain 8 -> 4 -> 0
  asm volatile("s_waitcnt vmcnt(8)" ::: "memory");
  __builtin_amdgcn_s_barrier();
  COMPUTE(1);                                          // t=29
  asm volatile("s_waitcnt vmcnt(4)" ::: "memory");
  __builtin_amdgcn_s_barrier();
  COMPUTE(2);                                          // t=30
  asm volatile("s_waitcnt vmcnt(0)" ::: "memory");
  __builtin_amdgcn_s_barrier();
  COMPUTE(3);                                          // t=31

  // epilogue: C/D layout col=lane&15, row=(lane>>4)*4+reg  (m89-verified)
  const int h0 = nt * 256 + wn + qm;
#pragma unroll
  for (int i = 0; i < 8; ++i) {
    const int rbase = wm + i * 16 + (lane >> 4) * 4;
#pragma unroll
    for (int r = 0; r < 4; ++r) {
      const int rl = rbase + r;
      if (rl < rows) {
        const int t = tok_s[rl];
        const float w = wt_s[rl];
        float* orow = out + (size_t)t * HIDDEN + h0;
#pragma unroll
        for (int j = 0; j < 4; ++j) {
          const float v = w * acc[i][j][r];
          unsafeAtomicAdd(orow + j * 16, v);   // native global_atomic_add_f32
        }
      }
    }
  }
}

// ---------------------------------------------------------------------------
extern "C" void kernel_launch(void* const* d_in, const int* in_sizes, int n_in,
                              void* d_out, int out_size, void* d_ws, size_t ws_size,
                              hipStream_t stream) {
  const float* x  = (const float*)d_in[0];
  const float* gw = (const float*)d_in[1];
  const float* ew = (const float*)d_in[2];
  float* out = (float*)d_out;

  // ws layout
  char* ws = (char*)d_ws;
  int*   cnt     = (int*)ws;                                           // 16 ints
  int*   echoice = (int*)(ws + 256);                                   // 2*8192 ints
  float* pchoice = (float*)(ws + 256 + (size_t)2 * NUM_TOKENS * 4);    // 2*8192 f32
  int*   tok = (int*)(ws + 256 + (size_t)4 * NUM_TOKENS * 4);          // 16*8192 ints
  float* wt  = (float*)(ws + 256 + (size_t)20 * NUM_TOKENS * 4);       // 16*8192 f32
  bf16*  xbf = (bf16*)(ws + 256 + (size_t)36 * NUM_TOKENS * 4);        // 16MB
  bf16*  wbf = (bf16*)((char*)xbf + (size_t)NUM_TOKENS * HIDDEN * 2);  // 16MB

  prep_kernel<<<6144, 256, 0, stream>>>(x, gw, ew, xbf, wbf, echoice, pchoice, out);
  build_lists_kernel<<<2 * NEXP, 1024, 0, stream>>>(echoice, pchoice, cnt, tok, wt);

  dim3 grid(HIDDEN / 256, NUM_TOKENS / 256, 2 * NEXP);
  moe_gemm_kernel<<<grid, 512, 0, stream>>>(xbf, wbf, cnt, tok, wt, out);
}

// Round 5
// 213.447 us; speedup vs baseline: 1.0489x; 1.0489x over previous
//
#include <hip/hip_runtime.h>
#include <hip/hip_bf16.h>
#include <stdint.h>

#define NUM_TOKENS 8192
#define HIDDEN 1024
#define NEXP 8
#define TOPK 2

typedef __bf16 bf16;
typedef __bf16 bf16x4 __attribute__((ext_vector_type(4)));
typedef __bf16 bf16x8 __attribute__((ext_vector_type(8)));
typedef float f32x4 __attribute__((ext_vector_type(4)));

// global -> LDS direct copy, 16B per lane. LDS dest must be lane-contiguous.
__device__ __forceinline__ void gld_lds16(const void* g, void* l) {
  __builtin_amdgcn_global_load_lds(
      (const __attribute__((address_space(1))) void*)(uintptr_t)g,
      (__attribute__((address_space(3))) void*)(uint32_t)(uintptr_t)l,
      16, 0, 0);
}

// ---------------------------------------------------------------------------
// Kernel 1 "prep": three independent jobs fused into one launch.
//   blocks [0,2048):    gating (fp32 exact) + x fp32->bf16     (one wave/token)
//   blocks [2048,4096): expert weights fp32->bf16              (16 elem/thread)
//   blocks [4096,6144): zero out                                (16 f32/thread)
// ---------------------------------------------------------------------------
__global__ __launch_bounds__(256) void prep_kernel(
    const float* __restrict__ x, const float* __restrict__ gw,
    const float* __restrict__ ew,
    bf16* __restrict__ xbf, bf16* __restrict__ wbf,
    int* __restrict__ echoice, float* __restrict__ pchoice,
    float* __restrict__ out)
{
  const int b   = blockIdx.x;
  const int tid = threadIdx.x;

  if (b < 2048) {
    // ---- gating + xbf ----
    const int wid  = tid >> 6;
    const int lane = tid & 63;
    const int t = b * 4 + wid;   // t in [0, 8192)

    const float* xrow = x + (size_t)t * HIDDEN;
    bf16* xbrow = xbf + (size_t)t * HIDDEN;

    float acc[NEXP];
#pragma unroll
    for (int e = 0; e < NEXP; ++e) acc[e] = 0.f;

#pragma unroll
    for (int it = 0; it < 4; ++it) {
      const int idx = it * 256 + lane * 4;
      float4 xv = *(const float4*)(xrow + idx);
      bf16x4 xb;
      xb[0] = (bf16)xv.x; xb[1] = (bf16)xv.y; xb[2] = (bf16)xv.z; xb[3] = (bf16)xv.w;
      *(bf16x4*)(xbrow + idx) = xb;
#pragma unroll
      for (int e = 0; e < NEXP; ++e) {
        float4 gv = *(const float4*)(gw + e * HIDDEN + idx);
        acc[e] += xv.x * gv.x + xv.y * gv.y + xv.z * gv.z + xv.w * gv.w;
      }
    }
#pragma unroll
    for (int e = 0; e < NEXP; ++e) {
#pragma unroll
      for (int off = 32; off > 0; off >>= 1)
        acc[e] += __shfl_xor(acc[e], off, 64);
    }

    if (lane == 0) {
      float m = acc[0];
#pragma unroll
      for (int e = 1; e < NEXP; ++e) m = fmaxf(m, acc[e]);
      float p[NEXP]; float s = 0.f;
#pragma unroll
      for (int e = 0; e < NEXP; ++e) { p[e] = expf(acc[e] - m); s += p[e]; }
      const float inv = 1.f / s;
#pragma unroll
      for (int e = 0; e < NEXP; ++e) p[e] *= inv;
      // top-2, ties -> lower index (jax.lax.top_k semantics)
      int i0 = 0; float p0 = p[0];
#pragma unroll
      for (int e = 1; e < NEXP; ++e) if (p[e] > p0) { p0 = p[e]; i0 = e; }
      int i1 = -1; float p1 = -1.f;
#pragma unroll
      for (int e = 0; e < NEXP; ++e) if (e != i0 && p[e] > p1) { p1 = p[e]; i1 = e; }

      echoice[t]              = i0;
      echoice[NUM_TOKENS + t] = i1;
      pchoice[t]              = p0;
      pchoice[NUM_TOKENS + t] = p1;
    }
  } else if (b < 4096) {
    // ---- expert weights fp32 -> bf16, 16 elems/thread ----
    const size_t i = ((size_t)(b - 2048) * 256 + tid) * 16;
    float4 v0 = *(const float4*)(ew + i);
    float4 v1 = *(const float4*)(ew + i + 4);
    float4 v2 = *(const float4*)(ew + i + 8);
    float4 v3 = *(const float4*)(ew + i + 12);
    bf16x8 o0, o1;
    o0[0] = (bf16)v0.x; o0[1] = (bf16)v0.y; o0[2] = (bf16)v0.z; o0[3] = (bf16)v0.w;
    o0[4] = (bf16)v1.x; o0[5] = (bf16)v1.y; o0[6] = (bf16)v1.z; o0[7] = (bf16)v1.w;
    o1[0] = (bf16)v2.x; o1[1] = (bf16)v2.y; o1[2] = (bf16)v2.z; o1[3] = (bf16)v2.w;
    o1[4] = (bf16)v3.x; o1[5] = (bf16)v3.y; o1[6] = (bf16)v3.z; o1[7] = (bf16)v3.w;
    *(bf16x8*)(wbf + i)     = o0;
    *(bf16x8*)(wbf + i + 8) = o1;
  } else {
    // ---- zero out (for the atomic GEMM epilogue), 16 f32/thread ----
    const size_t i = ((size_t)(b - 4096) * 256 + tid) * 16;
    const float4 z = {0.f, 0.f, 0.f, 0.f};
    *(float4*)(out + i)      = z;
    *(float4*)(out + i + 4)  = z;
    *(float4*)(out + i + 8)  = z;
    *(float4*)(out + i + 12) = z;
  }
}

// ---------------------------------------------------------------------------
// Kernel 1b: DETERMINISTIC compaction, 16 blocks (one per (k,expert) list).
// ---------------------------------------------------------------------------
__global__ __launch_bounds__(1024) void build_lists_kernel(
    const int* __restrict__ echoice, const float* __restrict__ pchoice,
    int* __restrict__ cnt, int* __restrict__ tok, float* __restrict__ wt)
{
  const int list = blockIdx.x;         // 0..15
  const int k = list >> 3;
  const int e = list & 7;
  const int tid  = threadIdx.x;
  const int wave = tid >> 6;           // 0..15
  const int lane = tid & 63;
  const int tbase = wave * 512;

  const int*   ec = echoice + k * NUM_TOKENS;
  const float* pc = pchoice + k * NUM_TOKENS;

  __shared__ int wcnt[16];
  __shared__ int woff[16];

  const unsigned long long lower = ((unsigned long long)1 << lane) - 1;

  int   ev[8];
  float pv[8];
#pragma unroll
  for (int c = 0; c < 8; ++c) {
    ev[c] = ec[tbase + c * 64 + lane];
    pv[c] = pc[tbase + c * 64 + lane];
  }
  unsigned long long m[8];
  int cl = 0;
#pragma unroll
  for (int c = 0; c < 8; ++c) { m[c] = __ballot(ev[c] == e); cl += __popcll(m[c]); }
  if (lane == 0) wcnt[wave] = cl;
  __syncthreads();
  if (tid == 0) {
    int off = 0;
#pragma unroll
    for (int w = 0; w < 16; ++w) { woff[w] = off; off += wcnt[w]; }
    cnt[list] = off;
  }
  __syncthreads();
  int run = woff[wave];
#pragma unroll
  for (int c = 0; c < 8; ++c) {
    if (ev[c] == e) {
      const int pos = run + __popcll(m[c] & lower);
      tok[(size_t)list * NUM_TOKENS + pos] = tbase + c * 64 + lane;
      wt [(size_t)list * NUM_TOKENS + pos] = pv[c];
    }
    run += __popcll(m[c]);
  }
}

// ---------------------------------------------------------------------------
// Kernel 2: grouped GEMM, 256x256 tile, FINE-GRAINED 2-sub-phase schedule.
// Round-5 diagnosis: R2 (128^2) was staging-BW-bound (delivered FLOP/byte ==
// tile intensity 64); R4 (256^2, coarse phases) had the intensity (128) but
// no intra-block overlap at 1 block/CU -> latency-serialized (m196 failure
// mode). m201/m248 show 1 block/CU 256^2 works iff the K-step is split into
// fine phases {ds_read || stage || MFMA} with barriers bracketing each MFMA
// cluster. This kernel = R4's verified geometry (same staging map, same
// PMC-verified zero-conflict swizzle, same vmcnt math) + the fine schedule:
//   step t (buf c=t&3):  vmcnt(8); barrier;
//     phase0: ds_read a[0..7],b[0..1]; STAGE A-halves(t+3); setprio{16 MFMA j=0,1}
//     barrier;
//     phase1: ds_read b[2..3];         STAGE B-halves(t+3); setprio{16 MFMA j=2,3}
// Safety: identical to R4 -- vmcnt(8) retires stage-t before the barrier;
// STAGE(t+3) overwrites buf (t-1)&3 whose reads retired last step.
// XCD-aware bijective block remap (2048 = 8*256) for L2 locality.
// Epilogue: native fp32 atomicAdd into zeroed out; exactly 2 contributions
// per element; fp32 add commutative -> deterministic.
// ---------------------------------------------------------------------------
__global__ __launch_bounds__(512, 2) void moe_gemm_kernel(
    const bf16* __restrict__ xbf, const bf16* __restrict__ wbf,
    const int* __restrict__ cnt, const int* __restrict__ tok,
    const float* __restrict__ wt, float* __restrict__ out)
{
  // XCD-aware bijective remap: flat = x + 4y + 128z in [0,2048); 2048%8==0.
  const int flat = blockIdx.x + (blockIdx.y << 2) + (blockIdx.z << 7);
  const int swz  = (flat & 7) * 256 + (flat >> 3);
  const int nt = swz & 3;
  const int mt = (swz >> 2) & 31;
  const int z  = swz >> 7;
  const int e  = z >> 1;
  const int k  = z & 1;
  const int list = k * NEXP + e;
  const int count = cnt[list];
  const int m0 = mt * 256;
  if (m0 >= count) return;
  const int rows = min(256, count - m0);

  __shared__ __align__(16) bf16 As[4 * 256 * 32];   // 4 x 16KB
  __shared__ __align__(16) bf16 Bs[4 * 256 * 32];   // 4 x 16KB
  __shared__ int   tok_s[256];
  __shared__ float wt_s[256];

  const int tid = threadIdx.x;
  if (tid < 256) {
    if (tid < rows) {
      tok_s[tid] = tok[(size_t)list * NUM_TOKENS + m0 + tid];
      wt_s[tid]  = wt [(size_t)list * NUM_TOKENS + m0 + tid];
    } else { tok_s[tid] = 0; wt_s[tid] = 0.f; }
  }
  __syncthreads();

  // staging: thread -> rows (tid>>2) and (tid>>2)+128, phys chunk tid&3.
  // LDS dest LINEAR (tid*16B; +4096 elems = rows [128,256)). Source carries
  // the inverse swizzle: srcChunk = (tid&3) ^ ((row>>1)&3)  [R4-verified,
  // SQ_LDS_BANK_CONFLICT == 0 on HW].
  const int csrc = (((tid & 3) ^ ((tid >> 3) & 3)) << 3);  // elems
  const int r0 = tid >> 2;                                 // [0,128)
  const bf16* gA0 = xbf + (size_t)tok_s[r0] * HIDDEN + csrc;
  const bf16* gA1 = xbf + (size_t)tok_s[r0 + 128] * HIDDEN + csrc;
  const bf16* gB0 = wbf + (size_t)e * HIDDEN * HIDDEN
                  + (size_t)(nt * 256 + r0) * HIDDEN + csrc;
  const bf16* gB1 = gB0 + (size_t)128 * HIDDEN;

  auto STAGE_A = [&](int t, int buf) {
    const int kc = t << 5;
    bf16* la = As + buf * 8192 + tid * 8;
    gld_lds16(gA0 + kc, la);
    gld_lds16(gA1 + kc, la + 4096);
  };
  auto STAGE_B = [&](int t, int buf) {
    const int kc = t << 5;
    bf16* lb = Bs + buf * 8192 + tid * 8;
    gld_lds16(gB0 + kc, lb);
    gld_lds16(gB1 + kc, lb + 4096);
  };

  const int wid  = tid >> 6;           // 0..7
  const int lane = tid & 63;
  const int wm = (wid >> 2) * 128;     // wave M-origin: 0 / 128
  const int wn = (wid & 3) * 64;       // wave N-origin: 0/64/128/192
  const int qm = lane & 15;            // m (or n) within 16
  const int l4 = lane >> 4;            // 8-elem k-chunk within 32

  f32x4 acc[8][4];
#pragma unroll
  for (int i = 0; i < 8; ++i)
#pragma unroll
    for (int j = 0; j < 4; ++j) acc[i][j] = (f32x4){0.f, 0.f, 0.f, 0.f};

  bf16x8 a[8], b2[2];

  auto LOAD_A = [&](int buf) {
    const bf16* Ab = As + buf * 8192;
#pragma unroll
    for (int i = 0; i < 8; ++i) {
      const int r = wm + i * 16 + qm;
      a[i] = *(const bf16x8*)(Ab + r * 32 + ((l4 ^ ((r >> 1) & 3)) << 3));
    }
  };
  auto LOAD_B2 = [&](int buf, int j0) {
    const bf16* Bb = Bs + buf * 8192;
#pragma unroll
    for (int j = 0; j < 2; ++j) {
      const int r = wn + (j0 + j) * 16 + qm;
      b2[j] = *(const bf16x8*)(Bb + r * 32 + ((l4 ^ ((r >> 1) & 3)) << 3));
    }
  };
  auto MFMA2 = [&](int j0) {
    __builtin_amdgcn_s_setprio(1);
#pragma unroll
    for (int i = 0; i < 8; ++i)
#pragma unroll
      for (int j = 0; j < 2; ++j)
        acc[i][j0 + j] = __builtin_amdgcn_mfma_f32_16x16x32_bf16(a[i], b2[j], acc[i][j0 + j], 0, 0, 0);
    __builtin_amdgcn_s_setprio(0);
  };

  // prologue: 3 stages (12 loads/thread) in flight
  STAGE_A(0, 0); STAGE_B(0, 0);
  STAGE_A(1, 1); STAGE_B(1, 1);
  STAGE_A(2, 2); STAGE_B(2, 2);

  // main loop: K=1024 -> 32 steps of BK=32; steady state keeps 2 stages
  // (8 loads/thread) in flight across every barrier (counted vmcnt).
#pragma unroll 1
  for (int t = 0; t < 29; ++t) {
    const int c  = t & 3;
    const int nb = (t + 3) & 3;
    asm volatile("s_waitcnt vmcnt(8)" ::: "memory");  // my stage-t loads done
    __builtin_amdgcn_s_barrier();                     // everyone's stage-t done
    // ---- phase 0: heavy ds_read + A-prefetch + half the MFMAs ----
    LOAD_A(c);
    LOAD_B2(c, 0);
    STAGE_A(t + 3, nb);
    MFMA2(0);
    __builtin_amdgcn_s_barrier();
    // ---- phase 1: light ds_read + B-prefetch + other half ----
    LOAD_B2(c, 2);
    STAGE_B(t + 3, nb);
    MFMA2(2);
  }
  // tail: drain 8 -> 4 -> 0 (no more staging)
  auto TAILSTEP = [&](int buf) {
    __builtin_amdgcn_s_barrier();
    LOAD_A(buf);
    LOAD_B2(buf, 0);
    MFMA2(0);
    __builtin_amdgcn_s_barrier();
    LOAD_B2(buf, 2);
    MFMA2(2);
  };
  asm volatile("s_waitcnt vmcnt(8)" ::: "memory");
  TAILSTEP(1);                                         // t=29
  asm volatile("s_waitcnt vmcnt(4)" ::: "memory");
  TAILSTEP(2);                                         // t=30
  asm volatile("s_waitcnt vmcnt(0)" ::: "memory");
  TAILSTEP(3);                                         // t=31

  // epilogue: C/D layout col=lane&15, row=(lane>>4)*4+reg  (m89-verified)
  const int h0 = nt * 256 + wn + qm;
#pragma unroll
  for (int i = 0; i < 8; ++i) {
    const int rbase = wm + i * 16 + (lane >> 4) * 4;
#pragma unroll
    for (int r = 0; r < 4; ++r) {
      const int rl = rbase + r;
      if (rl < rows) {
        const int t = tok_s[rl];
        const float w = wt_s[rl];
        float* orow = out + (size_t)t * HIDDEN + h0;
#pragma unroll
        for (int j = 0; j < 4; ++j) {
          const float v = w * acc[i][j][r];
          unsafeAtomicAdd(orow + j * 16, v);   // native global_atomic_add_f32
        }
      }
    }
  }
}

// ---------------------------------------------------------------------------
extern "C" void kernel_launch(void* const* d_in, const int* in_sizes, int n_in,
                              void* d_out, int out_size, void* d_ws, size_t ws_size,
                              hipStream_t stream) {
  const float* x  = (const float*)d_in[0];
  const float* gw = (const float*)d_in[1];
  const float* ew = (const float*)d_in[2];
  float* out = (float*)d_out;

  // ws layout
  char* ws = (char*)d_ws;
  int*   cnt     = (int*)ws;                                           // 16 ints
  int*   echoice = (int*)(ws + 256);                                   // 2*8192 ints
  float* pchoice = (float*)(ws + 256 + (size_t)2 * NUM_TOKENS * 4);    // 2*8192 f32
  int*   tok = (int*)(ws + 256 + (size_t)4 * NUM_TOKENS * 4);          // 16*8192 ints
  float* wt  = (float*)(ws + 256 + (size_t)20 * NUM_TOKENS * 4);       // 16*8192 f32
  bf16*  xbf = (bf16*)(ws + 256 + (size_t)36 * NUM_TOKENS * 4);        // 16MB
  bf16*  wbf = (bf16*)((char*)xbf + (size_t)NUM_TOKENS * HIDDEN * 2);  // 16MB

  prep_kernel<<<6144, 256, 0, stream>>>(x, gw, ew, xbf, wbf, echoice, pchoice, out);
  build_lists_kernel<<<2 * NEXP, 1024, 0, stream>>>(echoice, pchoice, cnt, tok, wt);

  dim3 grid(HIDDEN / 256, NUM_TOKENS / 256, 2 * NEXP);
  moe_gemm_kernel<<<grid, 512, 0, stream>>>(xbf, wbf, cnt, tok, wt, out);
}

// Round 6
// 206.201 us; speedup vs baseline: 1.0858x; 1.0351x over previous
//
#include <hip/hip_runtime.h>
#include <hip/hip_bf16.h>
#include <stdint.h>

#define NUM_TOKENS 8192
#define HIDDEN 1024
#define NEXP 8
#define TOPK 2

typedef __bf16 bf16;
typedef __bf16 bf16x4 __attribute__((ext_vector_type(4)));
typedef __bf16 bf16x8 __attribute__((ext_vector_type(8)));
typedef float f32x4 __attribute__((ext_vector_type(4)));

// global -> LDS direct copy, 16B per lane. LDS dest must be lane-contiguous.
__device__ __forceinline__ void gld_lds16(const void* g, void* l) {
  __builtin_amdgcn_global_load_lds(
      (const __attribute__((address_space(1))) void*)(uintptr_t)g,
      (__attribute__((address_space(3))) void*)(uint32_t)(uintptr_t)l,
      16, 0, 0);
}

// ---------------------------------------------------------------------------
// Kernel 1 "prep": three independent jobs fused into one launch.
//   blocks [0,2048):    gating (fp32 exact) + x fp32->bf16     (one wave/token)
//   blocks [2048,4096): expert weights fp32->bf16              (16 elem/thread)
//   blocks [4096,6144): zero out                                (16 f32/thread)
// ---------------------------------------------------------------------------
__global__ __launch_bounds__(256) void prep_kernel(
    const float* __restrict__ x, const float* __restrict__ gw,
    const float* __restrict__ ew,
    bf16* __restrict__ xbf, bf16* __restrict__ wbf,
    int* __restrict__ echoice, float* __restrict__ pchoice,
    float* __restrict__ out)
{
  const int b   = blockIdx.x;
  const int tid = threadIdx.x;

  if (b < 2048) {
    // ---- gating + xbf ----
    const int wid  = tid >> 6;
    const int lane = tid & 63;
    const int t = b * 4 + wid;   // t in [0, 8192)

    const float* xrow = x + (size_t)t * HIDDEN;
    bf16* xbrow = xbf + (size_t)t * HIDDEN;

    float acc[NEXP];
#pragma unroll
    for (int e = 0; e < NEXP; ++e) acc[e] = 0.f;

#pragma unroll
    for (int it = 0; it < 4; ++it) {
      const int idx = it * 256 + lane * 4;
      float4 xv = *(const float4*)(xrow + idx);
      bf16x4 xb;
      xb[0] = (bf16)xv.x; xb[1] = (bf16)xv.y; xb[2] = (bf16)xv.z; xb[3] = (bf16)xv.w;
      *(bf16x4*)(xbrow + idx) = xb;
#pragma unroll
      for (int e = 0; e < NEXP; ++e) {
        float4 gv = *(const float4*)(gw + e * HIDDEN + idx);
        acc[e] += xv.x * gv.x + xv.y * gv.y + xv.z * gv.z + xv.w * gv.w;
      }
    }
#pragma unroll
    for (int e = 0; e < NEXP; ++e) {
#pragma unroll
      for (int off = 32; off > 0; off >>= 1)
        acc[e] += __shfl_xor(acc[e], off, 64);
    }

    if (lane == 0) {
      float m = acc[0];
#pragma unroll
      for (int e = 1; e < NEXP; ++e) m = fmaxf(m, acc[e]);
      float p[NEXP]; float s = 0.f;
#pragma unroll
      for (int e = 0; e < NEXP; ++e) { p[e] = expf(acc[e] - m); s += p[e]; }
      const float inv = 1.f / s;
#pragma unroll
      for (int e = 0; e < NEXP; ++e) p[e] *= inv;
      // top-2, ties -> lower index (jax.lax.top_k semantics)
      int i0 = 0; float p0 = p[0];
#pragma unroll
      for (int e = 1; e < NEXP; ++e) if (p[e] > p0) { p0 = p[e]; i0 = e; }
      int i1 = -1; float p1 = -1.f;
#pragma unroll
      for (int e = 0; e < NEXP; ++e) if (e != i0 && p[e] > p1) { p1 = p[e]; i1 = e; }

      echoice[t]              = i0;
      echoice[NUM_TOKENS + t] = i1;
      pchoice[t]              = p0;
      pchoice[NUM_TOKENS + t] = p1;
    }
  } else if (b < 4096) {
    // ---- expert weights fp32 -> bf16, 16 elems/thread ----
    const size_t i = ((size_t)(b - 2048) * 256 + tid) * 16;
    float4 v0 = *(const float4*)(ew + i);
    float4 v1 = *(const float4*)(ew + i + 4);
    float4 v2 = *(const float4*)(ew + i + 8);
    float4 v3 = *(const float4*)(ew + i + 12);
    bf16x8 o0, o1;
    o0[0] = (bf16)v0.x; o0[1] = (bf16)v0.y; o0[2] = (bf16)v0.z; o0[3] = (bf16)v0.w;
    o0[4] = (bf16)v1.x; o0[5] = (bf16)v1.y; o0[6] = (bf16)v1.z; o0[7] = (bf16)v1.w;
    o1[0] = (bf16)v2.x; o1[1] = (bf16)v2.y; o1[2] = (bf16)v2.z; o1[3] = (bf16)v2.w;
    o1[4] = (bf16)v3.x; o1[5] = (bf16)v3.y; o1[6] = (bf16)v3.z; o1[7] = (bf16)v3.w;
    *(bf16x8*)(wbf + i)     = o0;
    *(bf16x8*)(wbf + i + 8) = o1;
  } else {
    // ---- zero out (for the atomic GEMM epilogue), 16 f32/thread ----
    const size_t i = ((size_t)(b - 4096) * 256 + tid) * 16;
    const float4 z = {0.f, 0.f, 0.f, 0.f};
    *(float4*)(out + i)      = z;
    *(float4*)(out + i + 4)  = z;
    *(float4*)(out + i + 8)  = z;
    *(float4*)(out + i + 12) = z;
  }
}

// ---------------------------------------------------------------------------
// Kernel 1b: DETERMINISTIC compaction, 16 blocks (one per (k,expert) list).
// ---------------------------------------------------------------------------
__global__ __launch_bounds__(1024) void build_lists_kernel(
    const int* __restrict__ echoice, const float* __restrict__ pchoice,
    int* __restrict__ cnt, int* __restrict__ tok, float* __restrict__ wt)
{
  const int list = blockIdx.x;         // 0..15
  const int k = list >> 3;
  const int e = list & 7;
  const int tid  = threadIdx.x;
  const int wave = tid >> 6;           // 0..15
  const int lane = tid & 63;
  const int tbase = wave * 512;

  const int*   ec = echoice + k * NUM_TOKENS;
  const float* pc = pchoice + k * NUM_TOKENS;

  __shared__ int wcnt[16];
  __shared__ int woff[16];

  const unsigned long long lower = ((unsigned long long)1 << lane) - 1;

  int   ev[8];
  float pv[8];
#pragma unroll
  for (int c = 0; c < 8; ++c) {
    ev[c] = ec[tbase + c * 64 + lane];
    pv[c] = pc[tbase + c * 64 + lane];
  }
  unsigned long long m[8];
  int cl = 0;
#pragma unroll
  for (int c = 0; c < 8; ++c) { m[c] = __ballot(ev[c] == e); cl += __popcll(m[c]); }
  if (lane == 0) wcnt[wave] = cl;
  __syncthreads();
  if (tid == 0) {
    int off = 0;
#pragma unroll
    for (int w = 0; w < 16; ++w) { woff[w] = off; off += wcnt[w]; }
    cnt[list] = off;
  }
  __syncthreads();
  int run = woff[wave];
#pragma unroll
  for (int c = 0; c < 8; ++c) {
    if (ev[c] == e) {
      const int pos = run + __popcll(m[c] & lower);
      tok[(size_t)list * NUM_TOKENS + pos] = tbase + c * 64 + lane;
      wt [(size_t)list * NUM_TOKENS + pos] = pv[c];
    }
    run += __popcll(m[c]);
  }
}

// ---------------------------------------------------------------------------
// Kernel 2: grouped GEMM, XCD-PINNED per expert.
// Round-6 diagnosis: delivered staging BW plateaus at ~6 TB/s across ALL
// schedules (R0/R2/R3) while m97-class kernels deliver 13.4 TB/s through
// the same global_load_lds path -> the wall is L3->L2 feed: default
// dispatch round-robins blocks of the same expert across all 8 XCDs, so
// each XCD's private L2 re-fetches the 2MB weight panel from L3.
// Fix: 8 experts <-> 8 XCDs. Flat 1D grid with blockIdx%8 == expert (the
// empirically-observed round-robin workgroup->XCD mapping): all blocks of
// expert e run on XCD e; its weight panel (2MB) + gathered x rows (~4MB)
// live in that XCD's 4MB L2 -> staging becomes L2-local. Perf-only
// heuristic: if the mapping differs, correctness is unaffected.
// Geometry = measured-best building blocks: 128x128 tile, BK=32,
// DOUBLE-buffered (33KB LDS -> 4 blocks/CU; per-expert useful blocks ~128
// = one full residency round on its 32 CUs), R3's PMC-verified
// zero-conflict source-swizzle, R2's verified stage-before-compute loop.
// Epilogue: native fp32 atomicAdd into zeroed out; exactly 2 contributions
// per element; fp32 add commutative -> deterministic.
// ---------------------------------------------------------------------------
__global__ __launch_bounds__(256, 4) void moe_gemm_kernel(
    const bf16* __restrict__ xbf, const bf16* __restrict__ wbf,
    const int* __restrict__ cnt, const int* __restrict__ tok,
    const float* __restrict__ wt, float* __restrict__ out)
{
  // flat = ((k*64 + mt)*8 + nt)*8 + e  ->  blockIdx%8 == e (XCD pin);
  // within an XCD, nt varies fastest -> consecutive co-XCD blocks share
  // the same A-rows (mt) while sweeping nt: A-tile L2 reuse too.
  const int e  = blockIdx.x & 7;
  const int g  = blockIdx.x >> 3;
  const int nt = g & 7;
  const int mt = (g >> 3) & 63;
  const int k  = g >> 9;
  const int list = k * NEXP + e;
  const int count = cnt[list];
  const int m0 = mt * 128;
  if (m0 >= count) return;
  const int rows = min(128, count - m0);

  __shared__ __align__(16) bf16 As[2][128 * 32];   // 2 x 8KB
  __shared__ __align__(16) bf16 Bs[2][128 * 32];   // 2 x 8KB
  __shared__ int   tok_s[128];
  __shared__ float wt_s[128];

  const int tid = threadIdx.x;
  if (tid < 128) {
    if (tid < rows) {
      tok_s[tid] = tok[(size_t)list * NUM_TOKENS + m0 + tid];
      wt_s[tid]  = wt [(size_t)list * NUM_TOKENS + m0 + tid];
    } else { tok_s[tid] = 0; wt_s[tid] = 0.f; }
  }
  __syncthreads();

  // staging: thread -> rows (tid>>2) and (tid>>2)+64, phys chunk tid&3.
  // LDS dest LINEAR (tid*16B; +2048 elems = rows [64,128)). Source carries
  // the inverse swizzle: srcChunk = (tid&3) ^ ((row>>1)&3)  [R3/R4-verified,
  // SQ_LDS_BANK_CONFLICT == 0 on HW].
  const int csrc = (((tid & 3) ^ ((tid >> 3) & 3)) << 3);  // elems
  const int r0 = tid >> 2;                                 // [0,64)
  const bf16* gA0 = xbf + (size_t)tok_s[r0] * HIDDEN + csrc;
  const bf16* gA1 = xbf + (size_t)tok_s[r0 + 64] * HIDDEN + csrc;
  const bf16* gB0 = wbf + (size_t)e * HIDDEN * HIDDEN
                  + (size_t)(nt * 128 + r0) * HIDDEN + csrc;
  const bf16* gB1 = gB0 + (size_t)64 * HIDDEN;

  auto STAGE = [&](int t, int buf) {
    const int kc = t << 5;
    bf16* la = &As[buf][0] + tid * 8;
    bf16* lb = &Bs[buf][0] + tid * 8;
    gld_lds16(gA0 + kc, la);
    gld_lds16(gA1 + kc, la + 2048);
    gld_lds16(gB0 + kc, lb);
    gld_lds16(gB1 + kc, lb + 2048);
  };

  const int wid  = tid >> 6;
  const int lane = tid & 63;
  const int wm = (wid >> 1) * 64;
  const int wn = (wid & 1) * 64;
  const int qm = lane & 15;          // m (or n) within 16
  const int l4 = lane >> 4;          // 8-elem k-chunk within 32

  f32x4 acc[4][4];
#pragma unroll
  for (int i = 0; i < 4; ++i)
#pragma unroll
    for (int j = 0; j < 4; ++j) acc[i][j] = (f32x4){0.f, 0.f, 0.f, 0.f};

  auto COMPUTE = [&](int buf) {
    const bf16* Ab = &As[buf][0];
    const bf16* Bb = &Bs[buf][0];
    bf16x8 a[4], b[4];
#pragma unroll
    for (int i = 0; i < 4; ++i) {
      const int r = wm + i * 16 + qm;
      a[i] = *(const bf16x8*)(Ab + r * 32 + ((l4 ^ ((r >> 1) & 3)) << 3));
    }
#pragma unroll
    for (int j = 0; j < 4; ++j) {
      const int r = wn + j * 16 + qm;
      b[j] = *(const bf16x8*)(Bb + r * 32 + ((l4 ^ ((r >> 1) & 3)) << 3));
    }
    __builtin_amdgcn_s_setprio(1);
#pragma unroll
    for (int i = 0; i < 4; ++i)
#pragma unroll
      for (int j = 0; j < 4; ++j)
        acc[i][j] = __builtin_amdgcn_mfma_f32_16x16x32_bf16(a[i], b[j], acc[i][j], 0, 0, 0);
    __builtin_amdgcn_s_setprio(0);
  };

  // R2-verified loop: stage(t+1) issued BEFORE compute(t); the single
  // end-of-step barrier (compiler drains vmcnt before s_barrier) lands
  // after a full compute phase of latency cover.
  STAGE(0, 0);
  __syncthreads();
#pragma unroll 1
  for (int t = 0; t < 32; ++t) {
    if (t < 31) STAGE(t + 1, (t + 1) & 1);
    COMPUTE(t & 1);
    if (t < 31) __syncthreads();
  }

  // epilogue: C/D layout col=lane&15, row=(lane>>4)*4+reg  (m89-verified)
  const int h0 = nt * 128 + wn + qm;
#pragma unroll
  for (int i = 0; i < 4; ++i) {
    const int rbase = wm + i * 16 + (lane >> 4) * 4;
#pragma unroll
    for (int r = 0; r < 4; ++r) {
      const int rl = rbase + r;
      if (rl < rows) {
        const int t = tok_s[rl];
        const float w = wt_s[rl];
        float* orow = out + (size_t)t * HIDDEN + h0;
#pragma unroll
        for (int j = 0; j < 4; ++j) {
          const float v = w * acc[i][j][r];
          unsafeAtomicAdd(orow + j * 16, v);   // native global_atomic_add_f32
        }
      }
    }
  }
}

// ---------------------------------------------------------------------------
extern "C" void kernel_launch(void* const* d_in, const int* in_sizes, int n_in,
                              void* d_out, int out_size, void* d_ws, size_t ws_size,
                              hipStream_t stream) {
  const float* x  = (const float*)d_in[0];
  const float* gw = (const float*)d_in[1];
  const float* ew = (const float*)d_in[2];
  float* out = (float*)d_out;

  // ws layout
  char* ws = (char*)d_ws;
  int*   cnt     = (int*)ws;                                           // 16 ints
  int*   echoice = (int*)(ws + 256);                                   // 2*8192 ints
  float* pchoice = (float*)(ws + 256 + (size_t)2 * NUM_TOKENS * 4);    // 2*8192 f32
  int*   tok = (int*)(ws + 256 + (size_t)4 * NUM_TOKENS * 4);          // 16*8192 ints
  float* wt  = (float*)(ws + 256 + (size_t)20 * NUM_TOKENS * 4);       // 16*8192 f32
  bf16*  xbf = (bf16*)(ws + 256 + (size_t)36 * NUM_TOKENS * 4);        // 16MB
  bf16*  wbf = (bf16*)((char*)xbf + (size_t)NUM_TOKENS * HIDDEN * 2);  // 16MB

  prep_kernel<<<6144, 256, 0, stream>>>(x, gw, ew, xbf, wbf, echoice, pchoice, out);
  build_lists_kernel<<<2 * NEXP, 1024, 0, stream>>>(echoice, pchoice, cnt, tok, wt);

  // flat 1D grid: blockIdx%8 == expert  ->  expert e pinned to XCD e.
  moe_gemm_kernel<<<8192, 256, 0, stream>>>(xbf, wbf, cnt, tok, wt, out);
}